// Round 1
// baseline (670.623 us; speedup 1.0000x reference)
//
#include <hip/hip_runtime.h>
#include <hip/hip_bf16.h>
#include <stdint.h>

typedef short s16x8 __attribute__((ext_vector_type(8)));
typedef float f32x4 __attribute__((ext_vector_type(4)));

#define H_ 16
#define DH 32
#define NTOK 49
#define CDIM 512
#define SCALE 0.17677669529663687f

__device__ __forceinline__ short f2bf(float f){
  union { float f; uint32_t u; } v; v.f = f;
  uint32_t r = v.u + 0x7fffu + ((v.u >> 16) & 1u);
  return (short)(r >> 16);
}

__device__ __forceinline__ s16x8 pack8(float4 a, float4 b){
  s16x8 r;
  r[0]=f2bf(a.x); r[1]=f2bf(a.y); r[2]=f2bf(a.z); r[3]=f2bf(a.w);
  r[4]=f2bf(b.x); r[5]=f2bf(b.y); r[6]=f2bf(b.z); r[7]=f2bf(b.w);
  return r;
}

// ---------------------------------------------------------------------------
// Kernel 1: qkv = x @ qkv_w.T + qkv_b, scattered to Q (scaled), K, V bf16
// tiles [CB][16][49][32]. Column space permuted: j' = s*512 + h*32 + d,
// original weight row = h*96 + d*3 + s. BM=128, BN=256, BK=32, 512 threads.
// grid = (CB*49/128) * 6, jt fastest so same-A blocks run together (L2 reuse).
// ---------------------------------------------------------------------------
__global__ __launch_bounds__(512)
void qkv_kernel(const float* __restrict__ x, const float* __restrict__ w,
                const float* __restrict__ bias,
                short* __restrict__ Q, short* __restrict__ Kt, short* __restrict__ V,
                int b0)
{
  __shared__ __align__(16) short As[2][128][40];
  __shared__ __align__(16) short Bs[2][256][40];
  const int tid = threadIdx.x;
  const int mt = blockIdx.x / 6, jt = blockIdx.x % 6;

  // A staging map: 128 rows x 32 k, 8 f32/thread
  const int ar = tid >> 2, ak = (tid & 3) << 3;
  const float* xrow = x + ((size_t)b0*NTOK + (size_t)mt*128 + ar)*CDIM + ak;
  // B staging map: 256 cols x 32 k, 16 f32/thread
  const int bc = tid >> 1, bk = (tid & 1) << 4;
  const int jp = jt*256 + bc;
  const int ps = jp >> 9, ph = (jp >> 5) & 15, pd = jp & 31;
  const float* wrow = w + (size_t)(ph*96 + pd*3 + ps)*CDIM + bk;

  const int wv = tid >> 6, lane = tid & 63;
  const int wr = wv >> 2, wc = wv & 3;        // wave grid 2 x 4
  const int lg = lane >> 4, lc = lane & 15;

  f32x4 acc[4][4];
  #pragma unroll
  for (int i=0;i<4;++i)
    #pragma unroll
    for (int j=0;j<4;++j) acc[i][j] = (f32x4){0.f,0.f,0.f,0.f};

  // prologue stage (k-step 0)
  {
    float4 a0 = *(const float4*)(xrow);
    float4 a1 = *(const float4*)(xrow+4);
    *(s16x8*)&As[0][ar][ak] = pack8(a0,a1);
    float4 q0 = *(const float4*)(wrow);
    float4 q1 = *(const float4*)(wrow+4);
    float4 q2 = *(const float4*)(wrow+8);
    float4 q3 = *(const float4*)(wrow+12);
    *(s16x8*)&Bs[0][bc][bk]   = pack8(q0,q1);
    *(s16x8*)&Bs[0][bc][bk+8] = pack8(q2,q3);
  }
  __syncthreads();
  int buf = 0;
  for (int st=0; st<16; ++st){
    if (st < 15){
      const float* xa = xrow + (st+1)*32;
      const float* wb = wrow + (st+1)*32;
      float4 a0 = *(const float4*)(xa);
      float4 a1 = *(const float4*)(xa+4);
      *(s16x8*)&As[buf^1][ar][ak] = pack8(a0,a1);
      float4 q0 = *(const float4*)(wb);
      float4 q1 = *(const float4*)(wb+4);
      float4 q2 = *(const float4*)(wb+8);
      float4 q3 = *(const float4*)(wb+12);
      *(s16x8*)&Bs[buf^1][bc][bk]   = pack8(q0,q1);
      *(s16x8*)&Bs[buf^1][bc][bk+8] = pack8(q2,q3);
    }
    s16x8 af[4], bfm[4];
    #pragma unroll
    for (int i=0;i<4;++i) af[i]  = *(const s16x8*)&As[buf][wr*64 + i*16 + lc][lg*8];
    #pragma unroll
    for (int j=0;j<4;++j) bfm[j] = *(const s16x8*)&Bs[buf][wc*64 + j*16 + lc][lg*8];
    #pragma unroll
    for (int i=0;i<4;++i)
      #pragma unroll
      for (int j=0;j<4;++j)
        acc[i][j] = __builtin_amdgcn_mfma_f32_16x16x32_bf16(af[i], bfm[j], acc[i][j], 0,0,0);
    __syncthreads();
    buf ^= 1;
  }

  // epilogue: bias (+scale for q), scatter to Q/K/V [bl][h][n][d] bf16
  const int s_sel = jt >> 1;                     // uniform per block
  short* dst = (s_sel==0) ? Q : (s_sel==1 ? Kt : V);
  const float fac = (s_sel==0) ? SCALE : 1.0f;
  int hj[4], dj[4]; float bsj[4];
  #pragma unroll
  for (int j=0;j<4;++j){
    int jp2 = jt*256 + wc*64 + j*16 + lc;
    hj[j] = (jp2 >> 5) & 15;
    dj[j] = jp2 & 31;
    bsj[j] = bias[hj[j]*96 + dj[j]*3 + s_sel];
  }
  #pragma unroll
  for (int i=0;i<4;++i){
    #pragma unroll
    for (int r=0;r<4;++r){
      int grow = mt*128 + wr*64 + i*16 + lg*4 + r;
      int bl = grow / 49;
      int n  = grow - bl*49;
      #pragma unroll
      for (int j=0;j<4;++j){
        float val = (acc[i][j][r] + bsj[j]) * fac;
        dst[(((size_t)bl*H_ + hj[j])*NTOK + n)*DH + dj[j]] = f2bf(val);
      }
    }
  }
}

// ---------------------------------------------------------------------------
// Kernel 2: per-(window, head) attention. One wave per (b,h), 4 waves/block.
// S = Qs@K^T (16 mfma, K=dh=32), + bias2 + mask, wave-parallel softmax,
// P->LDS(bf16)->A-frags, O = P@V, normalized rows -> AO [b][n][h*32+d] bf16.
// ---------------------------------------------------------------------------
__global__ __launch_bounds__(256)
void attn_kernel(const short* __restrict__ Q, const short* __restrict__ Kt,
                 const short* __restrict__ V, const float* __restrict__ bias2,
                 const float* __restrict__ mask, short* __restrict__ AO,
                 int b0, int nW)
{
  __shared__ __align__(16) short P[4][64][72];
  const int tid = threadIdx.x, wv = tid >> 6, lane = tid & 63;
  const int lg = lane >> 4, lc = lane & 15;
  const int pair = blockIdx.x*4 + wv;
  const int bl = pair >> 4, h = pair & 15;
  const short* q = Q  + ((size_t)bl*H_ + h)*NTOK*DH;
  const short* k = Kt + ((size_t)bl*H_ + h)*NTOK*DH;
  const short* v = V  + ((size_t)bl*H_ + h)*NTOK*DH;

  // QK^T
  s16x8 qa[4], kb[4];
  #pragma unroll
  for (int t=0;t<4;++t){
    int r = t*16 + lc; if (r > 48) r = 48;       // clamp pad rows -> real data
    qa[t] = *(const s16x8*)(q + r*DH + lg*8);
    kb[t] = *(const s16x8*)(k + r*DH + lg*8);
  }
  f32x4 S[4][4];
  #pragma unroll
  for (int i=0;i<4;++i)
    #pragma unroll
    for (int j=0;j<4;++j) S[i][j] = (f32x4){0.f,0.f,0.f,0.f};
  #pragma unroll
  for (int i=0;i<4;++i)
    #pragma unroll
    for (int j=0;j<4;++j)
      S[i][j] = __builtin_amdgcn_mfma_f32_16x16x32_bf16(qa[i], kb[j], S[i][j], 0,0,0);

  const float* bb = bias2 + (size_t)h*2401;
  const float* mm = mask + (size_t)((b0 + bl) % nW)*2401;

  float rinv[4][4];
  #pragma unroll
  for (int i=0;i<4;++i){
    #pragma unroll
    for (int r=0;r<4;++r){
      int row = i*16 + lg*4 + r;
      float mx = -3.0e38f;
      #pragma unroll
      for (int j=0;j<4;++j){
        int col = j*16 + lc;
        float sv = S[i][j][r];
        if (row < 49 && col < 49) sv += bb[row*49+col] + mm[row*49+col];
        else sv = -1.0e30f;
        S[i][j][r] = sv;
        mx = fmaxf(mx, sv);
      }
      #pragma unroll
      for (int off=1; off<16; off<<=1) mx = fmaxf(mx, __shfl_xor(mx, off, 64));
      float sum = 0.f;
      #pragma unroll
      for (int j=0;j<4;++j){
        float e = __expf(S[i][j][r] - mx);
        S[i][j][r] = e;
        sum += e;
      }
      #pragma unroll
      for (int off=1; off<16; off<<=1) sum += __shfl_xor(sum, off, 64);
      rinv[i][r] = 1.0f / sum;
    }
  }

  // P -> LDS (bf16, unnormalized)
  #pragma unroll
  for (int i=0;i<4;++i)
    #pragma unroll
    for (int j=0;j<4;++j)
      #pragma unroll
      for (int r=0;r<4;++r)
        P[wv][i*16 + lg*4 + r][j*16 + lc] = f2bf(S[i][j][r]);

  // V B-frags (clamped k), PV
  s16x8 vb[2][2];
  #pragma unroll
  for (int kt=0;kt<2;++kt)
    #pragma unroll
    for (int nt=0;nt<2;++nt){
      s16x8 t;
      #pragma unroll
      for (int e=0;e<8;++e){
        int kk = kt*32 + lg*8 + e; if (kk > 48) kk = 48;
        t[e] = v[kk*DH + nt*16 + lc];
      }
      vb[kt][nt] = t;
    }
  f32x4 O[4][2];
  #pragma unroll
  for (int i=0;i<4;++i){ O[i][0] = (f32x4){0.f,0.f,0.f,0.f}; O[i][1] = (f32x4){0.f,0.f,0.f,0.f}; }
  #pragma unroll
  for (int i=0;i<4;++i){
    #pragma unroll
    for (int kt=0;kt<2;++kt){
      s16x8 pa = *(const s16x8*)&P[wv][i*16 + lc][kt*32 + lg*8];
      #pragma unroll
      for (int nt=0;nt<2;++nt)
        O[i][nt] = __builtin_amdgcn_mfma_f32_16x16x32_bf16(pa, vb[kt][nt], O[i][nt], 0,0,0);
    }
  }
  #pragma unroll
  for (int i=0;i<4;++i)
    #pragma unroll
    for (int r=0;r<4;++r){
      int row = i*16 + lg*4 + r;
      if (row < 49){
        size_t o = ((size_t)bl*NTOK + row)*CDIM + h*DH;
        float rv = rinv[i][r];
        AO[o + lc]      = f2bf(O[i][0][r]*rv);
        AO[o + 16 + lc] = f2bf(O[i][1][r]*rv);
      }
    }
}

// ---------------------------------------------------------------------------
// Kernel 3: out = AO @ out_w.T + out_b (f32 out). BM=128, BN=256, BK=32.
// ---------------------------------------------------------------------------
__global__ __launch_bounds__(512)
void proj_kernel(const short* __restrict__ A, const float* __restrict__ w,
                 const float* __restrict__ bias, float* __restrict__ out, int b0)
{
  __shared__ __align__(16) short As[2][128][40];
  __shared__ __align__(16) short Bs[2][256][40];
  const int tid = threadIdx.x;
  const int mt = blockIdx.x >> 1, jt = blockIdx.x & 1;

  const int ar = tid >> 2, ak = (tid & 3) << 3;
  const short* arow = A + ((size_t)mt*128 + ar)*CDIM + ak;
  const int bc = tid >> 1, bk = (tid & 1) << 4;
  const float* wrow = w + (size_t)(jt*256 + bc)*CDIM + bk;

  const int wv = tid >> 6, lane = tid & 63;
  const int wr = wv >> 2, wc = wv & 3;
  const int lg = lane >> 4, lc = lane & 15;

  f32x4 acc[4][4];
  #pragma unroll
  for (int i=0;i<4;++i)
    #pragma unroll
    for (int j=0;j<4;++j) acc[i][j] = (f32x4){0.f,0.f,0.f,0.f};

  {
    *(s16x8*)&As[0][ar][ak] = *(const s16x8*)(arow);
    float4 q0 = *(const float4*)(wrow);
    float4 q1 = *(const float4*)(wrow+4);
    float4 q2 = *(const float4*)(wrow+8);
    float4 q3 = *(const float4*)(wrow+12);
    *(s16x8*)&Bs[0][bc][bk]   = pack8(q0,q1);
    *(s16x8*)&Bs[0][bc][bk+8] = pack8(q2,q3);
  }
  __syncthreads();
  int buf = 0;
  for (int st=0; st<16; ++st){
    if (st < 15){
      *(s16x8*)&As[buf^1][ar][ak] = *(const s16x8*)(arow + (st+1)*32);
      const float* wb = wrow + (st+1)*32;
      float4 q0 = *(const float4*)(wb);
      float4 q1 = *(const float4*)(wb+4);
      float4 q2 = *(const float4*)(wb+8);
      float4 q3 = *(const float4*)(wb+12);
      *(s16x8*)&Bs[buf^1][bc][bk]   = pack8(q0,q1);
      *(s16x8*)&Bs[buf^1][bc][bk+8] = pack8(q2,q3);
    }
    s16x8 af[4], bfm[4];
    #pragma unroll
    for (int i=0;i<4;++i) af[i]  = *(const s16x8*)&As[buf][wr*64 + i*16 + lc][lg*8];
    #pragma unroll
    for (int j=0;j<4;++j) bfm[j] = *(const s16x8*)&Bs[buf][wc*64 + j*16 + lc][lg*8];
    #pragma unroll
    for (int i=0;i<4;++i)
      #pragma unroll
      for (int j=0;j<4;++j)
        acc[i][j] = __builtin_amdgcn_mfma_f32_16x16x32_bf16(af[i], bfm[j], acc[i][j], 0,0,0);
    __syncthreads();
    buf ^= 1;
  }

  const int col0 = jt*256 + wc*64;
  float bsv[4];
  #pragma unroll
  for (int j=0;j<4;++j) bsv[j] = bias[col0 + j*16 + lc];
  #pragma unroll
  for (int i=0;i<4;++i){
    #pragma unroll
    for (int r=0;r<4;++r){
      int grow = mt*128 + wr*64 + i*16 + lg*4 + r;
      size_t o = ((size_t)b0*NTOK + grow)*CDIM + col0;
      #pragma unroll
      for (int j=0;j<4;++j)
        out[o + j*16 + lc] = acc[i][j][r] + bsv[j];
    }
  }
}

// bias2[h][r][c] = 2 * rp_bias_table[rp_index[r][c]][h]
__global__ void bias2_kernel(const int* __restrict__ idx, const float* __restrict__ tab,
                             float* __restrict__ b2)
{
  int i = blockIdx.x*256 + threadIdx.x;
  if (i < H_*2401){
    int h = i / 2401, rc = i - h*2401;
    b2[i] = 2.0f * tab[idx[rc]*H_ + h];
  }
}

extern "C" void kernel_launch(void* const* d_in, const int* in_sizes, int n_in,
                              void* d_out, int out_size, void* d_ws, size_t ws_size,
                              hipStream_t stream)
{
  const float* x      = (const float*)d_in[0];
  const float* qkv_w  = (const float*)d_in[1];
  const float* qkv_b  = (const float*)d_in[2];
  const int*   rp_idx = (const int*)d_in[3];
  const float* rp_tab = (const float*)d_in[4];
  const float* out_w  = (const float*)d_in[5];
  const float* out_b  = (const float*)d_in[6];
  const float* mask   = (const float*)d_in[7];
  const int nW = in_sizes[7] / (NTOK*NTOK);
  float* out = (float*)d_out;

  char* base = (char*)d_ws;
  float* b2 = (float*)base;
  size_t off = ((size_t)H_*2401*4 + 255) & ~(size_t)255;

  int CB = 512;  // windows per chunk; shrink if ws too small
  while (CB > 128){
    size_t need = off + (size_t)CB*H_*NTOK*DH*2*3 + (size_t)CB*NTOK*CDIM*2;
    if (need <= ws_size) break;
    CB >>= 1;
  }
  const size_t qs = (size_t)CB*H_*NTOK*DH*2;
  short* Q  = (short*)(base + off);
  short* K  = (short*)(base + off + qs);
  short* V  = (short*)(base + off + 2*qs);
  short* AO = (short*)(base + off + 3*qs);

  hipLaunchKernelGGL(bias2_kernel, dim3((H_*2401 + 255)/256), dim3(256), 0, stream,
                     rp_idx, rp_tab, b2);

  const int nchunk = 2048 / CB;
  const int mtiles = CB*NTOK/128;
  for (int c=0; c<nchunk; ++c){
    int b0 = c*CB;
    hipLaunchKernelGGL(qkv_kernel, dim3(mtiles*6), dim3(512), 0, stream,
                       x, qkv_w, qkv_b, Q, K, V, b0);
    hipLaunchKernelGGL(attn_kernel, dim3(CB*4), dim3(256), 0, stream,
                       Q, K, V, b2, mask, AO, b0, nW);
    hipLaunchKernelGGL(proj_kernel, dim3(mtiles*2), dim3(512), 0, stream,
                       AO, out_w, out_b, out, b0);
  }
}

// Round 2
// 605.219 us; speedup vs baseline: 1.1081x; 1.1081x over previous
//
#include <hip/hip_runtime.h>
#include <hip/hip_bf16.h>
#include <stdint.h>

typedef short s16x8 __attribute__((ext_vector_type(8)));
typedef float f32x4 __attribute__((ext_vector_type(4)));

#define H_ 16
#define DH 32
#define NTOK 49
#define CDIM 512
#define SCALE 0.17677669529663687f

typedef const __attribute__((address_space(1))) uint32_t* gas_ptr;
typedef __attribute__((address_space(3))) uint32_t* las_ptr;
#define GLL16(g, l) __builtin_amdgcn_global_load_lds((gas_ptr)(g), (las_ptr)(l), 16, 0, 0)

__device__ __forceinline__ short f2bf(float f){
  union { float f; uint32_t u; } v; v.f = f;
  uint32_t r = v.u + 0x7fffu + ((v.u >> 16) & 1u);
  return (short)(r >> 16);
}

__device__ __forceinline__ s16x8 pack8(float4 a, float4 b){
  s16x8 r;
  r[0]=f2bf(a.x); r[1]=f2bf(a.y); r[2]=f2bf(a.z); r[3]=f2bf(a.w);
  r[4]=f2bf(b.x); r[5]=f2bf(b.y); r[6]=f2bf(b.z); r[7]=f2bf(b.w);
  return r;
}

// ---------------------------------------------------------------------------
// Prep kernels (run once)
// ---------------------------------------------------------------------------
// wq[j'][k] bf16, j' = s*512 + h*32 + d  <- qkv_w[h*96+d*3+s][k] * (s==0?SCALE:1)
// pb[j'] = qkv_b[h*96+d*3+s] * (s==0?SCALE:1)
__global__ void prep_wq_kernel(const float* __restrict__ w, const float* __restrict__ b,
                               short* __restrict__ wq, float* __restrict__ pb)
{
  int t = blockIdx.x*256 + threadIdx.x;        // [0, 1536*64)
  int jp = t >> 6, kg = t & 63;
  int s = jp >> 9, h = (jp >> 5) & 15, d = jp & 31;
  int srow = h*96 + d*3 + s;
  float fac = (s == 0) ? SCALE : 1.0f;
  const float* wr = w + (size_t)srow*CDIM + kg*8;
  float4 a = *(const float4*)wr;
  float4 c = *(const float4*)(wr+4);
  a.x*=fac; a.y*=fac; a.z*=fac; a.w*=fac;
  c.x*=fac; c.y*=fac; c.z*=fac; c.w*=fac;
  ((s16x8*)(wq + (size_t)jp*CDIM))[kg] = pack8(a,c);
  if (kg == 0) pb[jp] = b[srow]*fac;
}

__global__ void prep_wo_kernel(const float* __restrict__ w, short* __restrict__ wo)
{
  int t = blockIdx.x*256 + threadIdx.x;        // [0, 512*64)
  int j = t >> 6, kg = t & 63;
  const float* wr = w + (size_t)j*CDIM + kg*8;
  float4 a = *(const float4*)wr;
  float4 c = *(const float4*)(wr+4);
  ((s16x8*)(wo + (size_t)j*CDIM))[kg] = pack8(a,c);
}

// bias2[h][r][c] = 2 * rp_bias_table[rp_index[r][c]][h]
__global__ void bias2_kernel(const int* __restrict__ idx, const float* __restrict__ tab,
                             float* __restrict__ b2)
{
  int i = blockIdx.x*256 + threadIdx.x;
  if (i < H_*2401){
    int h = i / 2401, rc = i - h*2401;
    b2[i] = 2.0f * tab[idx[rc]*H_ + h];
  }
}

// f32 -> bf16 convert (chunk of x)
__global__ void cvt_kernel(const float* __restrict__ src, short* __restrict__ dst, int n8)
{
  int i = blockIdx.x*blockDim.x + threadIdx.x;
  int stride = gridDim.x*blockDim.x;
  for (; i < n8; i += stride){
    float4 a = ((const float4*)src)[2*i];
    float4 b = ((const float4*)src)[2*i+1];
    ((s16x8*)dst)[i] = pack8(a,b);
  }
}

// ---------------------------------------------------------------------------
// m97-structure GEMM: C[128 x 128] tile, BK=64, 256 threads (4 waves 2x2),
// global_load_lds width-16 staging, 2 barriers per K-step. K = 512 fixed.
// A: [M][512] bf16 row-major. B: [Ncols][512] bf16 row-major (row = out col).
// EPI 0: qkv scatter epilogue (Q/K/V per-head bf16 + pbias). EPI 1: f32 out.
// ---------------------------------------------------------------------------
template<int EPI>
__global__ __launch_bounds__(256)
void gemm128(const short* __restrict__ A, const short* __restrict__ Bm,
             const float* __restrict__ pb,
             short* __restrict__ Q, short* __restrict__ Kd, short* __restrict__ V,
             float* __restrict__ outF, int ntiles, int b0)
{
  __shared__ __align__(16) short As[128*64];
  __shared__ __align__(16) short Bs[128*64];
  const int tid = threadIdx.x, w = tid >> 6, l = tid & 63;
  const int mt = blockIdx.x / ntiles, jt = blockIdx.x % ntiles;
  const int wr = w >> 1, wc = w & 1, lg = l >> 4, lc = l & 15;

  // staging maps: issue i covers rows [i*32, i*32+32), wave w rows w*8..w*8+7
  const int srow = w*8 + (l >> 3);
  const int kb = (l & 7) * 16;                  // byte offset within 128B k-row
  const char* ga = (const char*)A  + ((size_t)(mt*128 + srow))*1024 + kb;
  const char* gb = (const char*)Bm + ((size_t)(jt*128 + srow))*1024 + kb;

  f32x4 acc[4][4];
  #pragma unroll
  for (int i=0;i<4;++i)
    #pragma unroll
    for (int j=0;j<4;++j) acc[i][j] = (f32x4){0.f,0.f,0.f,0.f};

  for (int kt=0; kt<8; ++kt){
    const char* gak = ga + kt*128;
    const char* gbk = gb + kt*128;
    #pragma unroll
    for (int i=0;i<4;++i){
      GLL16(gak + i*32768, As + i*2048 + w*512);
      GLL16(gbk + i*32768, Bs + i*2048 + w*512);
    }
    __syncthreads();
    #pragma unroll
    for (int kk=0; kk<2; ++kk){
      s16x8 af[4], bf_[4];
      #pragma unroll
      for (int i=0;i<4;++i) af[i]  = *(const s16x8*)&As[(wr*64 + i*16 + lc)*64 + kk*32 + lg*8];
      #pragma unroll
      for (int j=0;j<4;++j) bf_[j] = *(const s16x8*)&Bs[(wc*64 + j*16 + lc)*64 + kk*32 + lg*8];
      #pragma unroll
      for (int i=0;i<4;++i)
        #pragma unroll
        for (int j=0;j<4;++j)
          acc[i][j] = __builtin_amdgcn_mfma_f32_16x16x32_bf16(af[i], bf_[j], acc[i][j], 0,0,0);
    }
    __syncthreads();
  }

  const int cb = jt*128 + wc*64;
  if (EPI == 0){
    const int s_sel = cb >> 9;                 // uniform per block
    short* dst = (s_sel==0) ? Q : (s_sel==1 ? Kd : V);
    float bv[4]; int hj[4], dj[4];
    #pragma unroll
    for (int j=0;j<4;++j){
      int cc = cb + j*16 + lc;
      bv[j] = pb[cc];
      hj[j] = (cc >> 5) & 15;
      dj[j] = cc & 31;
    }
    #pragma unroll
    for (int i=0;i<4;++i){
      #pragma unroll
      for (int r=0;r<4;++r){
        int grow = mt*128 + wr*64 + i*16 + lg*4 + r;
        int bl = grow / 49;
        int n  = grow - bl*49;
        #pragma unroll
        for (int j=0;j<4;++j)
          dst[(((size_t)bl*H_ + hj[j])*NTOK + n)*DH + dj[j]] = f2bf(acc[i][j][r] + bv[j]);
      }
    }
  } else {
    float bv[4];
    #pragma unroll
    for (int j=0;j<4;++j) bv[j] = pb[cb + j*16 + lc];
    #pragma unroll
    for (int i=0;i<4;++i){
      #pragma unroll
      for (int r=0;r<4;++r){
        int grow = mt*128 + wr*64 + i*16 + lg*4 + r;
        size_t o = ((size_t)(b0*NTOK) + grow)*CDIM + cb;
        #pragma unroll
        for (int j=0;j<4;++j)
          outF[o + j*16 + lc] = acc[i][j][r] + bv[j];
      }
    }
  }
}

// ---------------------------------------------------------------------------
// Kernel 2: per-(window, head) attention. One wave per (b,h), 4 waves/block.
// ---------------------------------------------------------------------------
__global__ __launch_bounds__(256)
void attn_kernel(const short* __restrict__ Q, const short* __restrict__ Kt,
                 const short* __restrict__ V, const float* __restrict__ bias2,
                 const float* __restrict__ mask, short* __restrict__ AO,
                 int b0, int nW)
{
  __shared__ __align__(16) short P[4][64][72];
  const int tid = threadIdx.x, wv = tid >> 6, lane = tid & 63;
  const int lg = lane >> 4, lc = lane & 15;
  const int pair = blockIdx.x*4 + wv;
  const int bl = pair >> 4, h = pair & 15;
  const short* q = Q  + ((size_t)bl*H_ + h)*NTOK*DH;
  const short* k = Kt + ((size_t)bl*H_ + h)*NTOK*DH;
  const short* v = V  + ((size_t)bl*H_ + h)*NTOK*DH;

  s16x8 qa[4], kb[4];
  #pragma unroll
  for (int t=0;t<4;++t){
    int r = t*16 + lc; if (r > 48) r = 48;
    qa[t] = *(const s16x8*)(q + r*DH + lg*8);
    kb[t] = *(const s16x8*)(k + r*DH + lg*8);
  }
  f32x4 S[4][4];
  #pragma unroll
  for (int i=0;i<4;++i)
    #pragma unroll
    for (int j=0;j<4;++j) S[i][j] = (f32x4){0.f,0.f,0.f,0.f};
  #pragma unroll
  for (int i=0;i<4;++i)
    #pragma unroll
    for (int j=0;j<4;++j)
      S[i][j] = __builtin_amdgcn_mfma_f32_16x16x32_bf16(qa[i], kb[j], S[i][j], 0,0,0);

  const float* bb = bias2 + (size_t)h*2401;
  const float* mm = mask + (size_t)((b0 + bl) % nW)*2401;

  float rinv[4][4];
  #pragma unroll
  for (int i=0;i<4;++i){
    #pragma unroll
    for (int r=0;r<4;++r){
      int row = i*16 + lg*4 + r;
      float mx = -3.0e38f;
      #pragma unroll
      for (int j=0;j<4;++j){
        int col = j*16 + lc;
        float sv = S[i][j][r];
        if (row < 49 && col < 49) sv += bb[row*49+col] + mm[row*49+col];
        else sv = -1.0e30f;
        S[i][j][r] = sv;
        mx = fmaxf(mx, sv);
      }
      #pragma unroll
      for (int off=1; off<16; off<<=1) mx = fmaxf(mx, __shfl_xor(mx, off, 64));
      float sum = 0.f;
      #pragma unroll
      for (int j=0;j<4;++j){
        float e = __expf(S[i][j][r] - mx);
        S[i][j][r] = e;
        sum += e;
      }
      #pragma unroll
      for (int off=1; off<16; off<<=1) sum += __shfl_xor(sum, off, 64);
      rinv[i][r] = 1.0f / sum;
    }
  }

  #pragma unroll
  for (int i=0;i<4;++i)
    #pragma unroll
    for (int j=0;j<4;++j)
      #pragma unroll
      for (int r=0;r<4;++r)
        P[wv][i*16 + lg*4 + r][j*16 + lc] = f2bf(S[i][j][r]);

  s16x8 vb[2][2];
  #pragma unroll
  for (int kt=0;kt<2;++kt)
    #pragma unroll
    for (int nt=0;nt<2;++nt){
      s16x8 t;
      #pragma unroll
      for (int e=0;e<8;++e){
        int kk = kt*32 + lg*8 + e; if (kk > 48) kk = 48;
        t[e] = v[kk*DH + nt*16 + lc];
      }
      vb[kt][nt] = t;
    }
  f32x4 O[4][2];
  #pragma unroll
  for (int i=0;i<4;++i){ O[i][0] = (f32x4){0.f,0.f,0.f,0.f}; O[i][1] = (f32x4){0.f,0.f,0.f,0.f}; }
  #pragma unroll
  for (int i=0;i<4;++i){
    #pragma unroll
    for (int kt=0;kt<2;++kt){
      s16x8 pa = *(const s16x8*)&P[wv][i*16 + lc][kt*32 + lg*8];
      #pragma unroll
      for (int nt=0;nt<2;++nt)
        O[i][nt] = __builtin_amdgcn_mfma_f32_16x16x32_bf16(pa, vb[kt][nt], O[i][nt], 0,0,0);
    }
  }
  #pragma unroll
  for (int i=0;i<4;++i)
    #pragma unroll
    for (int r=0;r<4;++r){
      int row = i*16 + lg*4 + r;
      if (row < 49){
        size_t o = ((size_t)bl*NTOK + row)*CDIM + h*DH;
        float rv = rinv[i][r];
        AO[o + lc]      = f2bf(O[i][0][r]*rv);
        AO[o + 16 + lc] = f2bf(O[i][1][r]*rv);
      }
    }
}

extern "C" void kernel_launch(void* const* d_in, const int* in_sizes, int n_in,
                              void* d_out, int out_size, void* d_ws, size_t ws_size,
                              hipStream_t stream)
{
  const float* x      = (const float*)d_in[0];
  const float* qkv_w  = (const float*)d_in[1];
  const float* qkv_b  = (const float*)d_in[2];
  const int*   rp_idx = (const int*)d_in[3];
  const float* rp_tab = (const float*)d_in[4];
  const float* out_w  = (const float*)d_in[5];
  const float* out_b  = (const float*)d_in[6];
  const float* mask   = (const float*)d_in[7];
  const int nW = in_sizes[7] / (NTOK*NTOK);
  float* out = (float*)d_out;

  char* base = (char*)d_ws;
  size_t off = 0;
  auto alloc = [&](size_t bytes)->char*{
    char* p = base + off;
    off = (off + bytes + 255) & ~(size_t)255;
    return p;
  };
  float* b2  = (float*)alloc((size_t)H_*2401*4);
  short* wq  = (short*)alloc((size_t)1536*CDIM*2);
  float* pbq = (float*)alloc(1536*4);
  short* wo  = (short*)alloc((size_t)CDIM*CDIM*2);

  int CB = 512;
  while (CB > 128){
    size_t need = off + 5*(size_t)CB*50176;
    if (need <= ws_size) break;
    CB >>= 1;
  }
  short* xb = (short*)alloc((size_t)CB*50176);
  short* Q  = (short*)alloc((size_t)CB*50176);
  short* K  = (short*)alloc((size_t)CB*50176);
  short* V  = (short*)alloc((size_t)CB*50176);
  short* AO = (short*)alloc((size_t)CB*50176);

  hipLaunchKernelGGL(bias2_kernel, dim3((H_*2401 + 255)/256), dim3(256), 0, stream,
                     rp_idx, rp_tab, b2);
  hipLaunchKernelGGL(prep_wq_kernel, dim3(1536*64/256), dim3(256), 0, stream,
                     qkv_w, qkv_b, wq, pbq);
  hipLaunchKernelGGL(prep_wo_kernel, dim3(512*64/256), dim3(256), 0, stream,
                     out_w, wo);

  const int nchunk = 2048 / CB;
  const int mtiles = CB*NTOK/128;
  const int n8 = CB*3136;
  for (int c=0; c<nchunk; ++c){
    int b0 = c*CB;
    hipLaunchKernelGGL(cvt_kernel, dim3(2048), dim3(256), 0, stream,
                       x + (size_t)b0*NTOK*CDIM, xb, n8);
    hipLaunchKernelGGL((gemm128<0>), dim3(mtiles*12), dim3(256), 0, stream,
                       xb, wq, pbq, Q, K, V, (float*)nullptr, 12, b0);
    hipLaunchKernelGGL(attn_kernel, dim3(CB*4), dim3(256), 0, stream,
                       Q, K, V, b2, mask, AO, b0, nW);
    hipLaunchKernelGGL((gemm128<1>), dim3(mtiles*4), dim3(256), 0, stream,
                       AO, wo, out_b, (short*)nullptr, (short*)nullptr, (short*)nullptr,
                       out, 4, b0);
  }
}